// Round 3
// baseline (377.509 us; speedup 1.0000x reference)
//
#include <hip/hip_runtime.h>

typedef __attribute__((ext_vector_type(8))) short short8;
typedef __attribute__((ext_vector_type(4))) float f32x4;

static __device__ __forceinline__ short f2bf(float x) {
  union { float f; unsigned u; } v; v.f = x;
  unsigned r = (v.u + 0x7fffu + ((v.u >> 16) & 1u)) >> 16;
  return (short)r;
}

__global__ __launch_bounds__(256) void convert_f32_bf16(const float* __restrict__ src,
                                                        short* __restrict__ dst, int n8) {
  int i = blockIdx.x * 256 + threadIdx.x;
  if (i >= n8) return;
  const f32x4* s = (const f32x4*)(src + (long)i * 8);
  f32x4 a = s[0], b = s[1];
  short8 o;
  o[0] = f2bf(a[0]); o[1] = f2bf(a[1]); o[2] = f2bf(a[2]); o[3] = f2bf(a[3]);
  o[4] = f2bf(b[0]); o[5] = f2bf(b[1]); o[6] = f2bf(b[2]); o[7] = f2bf(b[3]);
  *(short8*)(dst + (long)i * 8) = o;
}

// C[M,N] = scale * A[M,K] @ B[N,K]^T + bias + resid.
// A: f32 (AF32, converted during staging) or bf16. B: bf16 [N][K].
// OMODE 0: C[row*ldc + col]; OMODE 1: vt store C[(row>>10)<<20 | col<<10 | row&1023].
// 64x64x64 tile, 4 waves (each 16 rows x 64 cols), grid flattened + XCD swizzle.
template <int OMODE, bool AF32, typename OutT>
__global__ __launch_bounds__(256) void gemm_mfma(
    const void* __restrict__ Abase, int lda,
    const short* __restrict__ Bbase, int ldb,
    OutT* __restrict__ Cbase, int ldc,
    const float* __restrict__ bias,
    const float* __restrict__ resid, int ldres,
    float scale, int K, int nbn) {
  constexpr int LDK = 72;
  __shared__ short As[64 * LDK];
  __shared__ short Bs[64 * LDK];

  // XCD-bijective swizzle (nwg % 8 == 0)
  const int nwg = gridDim.x;
  const int cpx = nwg >> 3;
  int bid = blockIdx.x;
  bid = (bid & 7) * cpx + (bid >> 3);
  const int bn = (bid % nbn) * 64, bm = (bid / nbn) * 64;

  const int tid = threadIdx.x, lane = tid & 63, wave = tid >> 6;
  const int fr = lane & 15, khi = lane >> 4;
  const int srow = tid >> 3, scol = (tid & 7) * 8;

  const short* A16 = AF32 ? nullptr : (const short*)Abase;
  const float* A32 = AF32 ? (const float*)Abase : nullptr;

  f32x4 acc[4];
#pragma unroll
  for (int n = 0; n < 4; ++n) acc[n] = (f32x4){0.f, 0.f, 0.f, 0.f};

  for (int k0 = 0; k0 < K; k0 += 64) {
#pragma unroll
    for (int it = 0; it < 2; ++it) {
      int r = it * 32 + srow;
      if (!AF32) {
        *(short8*)&As[r * LDK + scol] =
            *(const short8*)(A16 + (long)(bm + r) * lda + k0 + scol);
      } else {
        const float* p = A32 + (long)(bm + r) * lda + k0 + scol;
        f32x4 x = *(const f32x4*)p, y = *(const f32x4*)(p + 4);
        short8 o;
        o[0] = f2bf(x[0]); o[1] = f2bf(x[1]); o[2] = f2bf(x[2]); o[3] = f2bf(x[3]);
        o[4] = f2bf(y[0]); o[5] = f2bf(y[1]); o[6] = f2bf(y[2]); o[7] = f2bf(y[3]);
        *(short8*)&As[r * LDK + scol] = o;
      }
      *(short8*)&Bs[r * LDK + scol] =
          *(const short8*)(Bbase + (long)(bn + r) * ldb + k0 + scol);
    }
    __syncthreads();
#pragma unroll
    for (int ks = 0; ks < 64; ks += 32) {
      short8 af = *(const short8*)&As[(wave * 16 + fr) * LDK + ks + khi * 8];
#pragma unroll
      for (int n = 0; n < 4; ++n) {
        short8 bf = *(const short8*)&Bs[(n * 16 + fr) * LDK + ks + khi * 8];
        acc[n] = __builtin_amdgcn_mfma_f32_16x16x32_bf16(af, bf, acc[n], 0, 0, 0);
      }
    }
    __syncthreads();
  }

  const int col0 = lane & 15, row0 = (lane >> 4) * 4;
#pragma unroll
  for (int n = 0; n < 4; ++n) {
    int gcol = bn + n * 16 + col0;
    float bi = bias ? bias[gcol] : 0.f;
#pragma unroll
    for (int i = 0; i < 4; ++i) {
      int grow = bm + wave * 16 + row0 + i;
      float v = acc[n][i] * scale + bi;
      if (resid) v += resid[(long)grow * ldres + gcol];
      long addr;
      if (OMODE == 0)
        addr = (long)grow * ldc + gcol;
      else
        addr = ((long)(grow >> 10) << 20) + ((long)gcol << 10) + (grow & 1023);
      if constexpr (sizeof(OutT) == 2)
        Cbase[addr] = (OutT)f2bf(v);
      else
        Cbase[addr] = v;
    }
  }
}

// Fused attention, barrier-free: per block (z = b*16+g, 64 q-rows), 4 independent
// waves of 16 q-rows each. K/V fragments read directly from L2/L1; P in per-wave
// private LDS. Two-pass online softmax with QK^T recompute.
__global__ __launch_bounds__(256, 4) void fused_attn(
    const short* __restrict__ qb,   // [4][1024][1024] bf16, feat = g*64+d
    const short* __restrict__ kb,   // [4][1024][1024] bf16, feat = g*64+d
    const short* __restrict__ vt,   // [4][1024][1024] bf16, vt[b][d*16+g][t]
    float* __restrict__ scores,     // [64][1024][1024] f32
    short* __restrict__ at) {       // [4][1024][1024] bf16, feat = d*16+g
  constexpr int LP = 136;
  __shared__ short Ps[64 * LP];

  // XCD swizzle: 128 consecutive blocks (8 z's) per XCD -> 2MB L2 working set
  int bid = blockIdx.x;
  bid = (bid & 7) * 128 + (bid >> 3);
  const int z = bid >> 4, b = z >> 4, g = z & 15;
  const int q0 = (bid & 15) * 64;

  const int tid = threadIdx.x, lane = tid & 63, w = tid >> 6;
  const int fr = lane & 15, khi = lane >> 4;
  const long bqk = (long)b << 20;

  const short* qrow = qb + bqk + (long)(q0 + w * 16 + fr) * 1024 + g * 64 + khi * 8;
  short8 aq0 = *(const short8*)qrow;
  short8 aq1 = *(const short8*)(qrow + 32);

  const short* kg = kb + bqk + g * 64 + khi * 8;

  float m4[4] = {-3.4e38f, -3.4e38f, -3.4e38f, -3.4e38f};
  float s4[4] = {0.f, 0.f, 0.f, 0.f};

  // ---- pass 1: online max+sum ----
  for (int t0 = 0; t0 < 1024; t0 += 128) {
    f32x4 sacc[8];
#pragma unroll
    for (int nf = 0; nf < 8; ++nf) sacc[nf] = (f32x4){0.f, 0.f, 0.f, 0.f};
#pragma unroll
    for (int nf = 0; nf < 8; ++nf) {
      const short* kr = kg + (long)(t0 + nf * 16 + fr) * 1024;
      short8 b0 = *(const short8*)kr;
      short8 b1 = *(const short8*)(kr + 32);
      sacc[nf] = __builtin_amdgcn_mfma_f32_16x16x32_bf16(aq0, b0, sacc[nf], 0, 0, 0);
      sacc[nf] = __builtin_amdgcn_mfma_f32_16x16x32_bf16(aq1, b1, sacc[nf], 0, 0, 0);
    }
#pragma unroll
    for (int i = 0; i < 4; ++i) {
      float tm = sacc[0][i];
#pragma unroll
      for (int nf = 1; nf < 8; ++nf) tm = fmaxf(tm, sacc[nf][i]);
      tm *= 0.125f;
      tm = fmaxf(tm, __shfl_xor(tm, 1));
      tm = fmaxf(tm, __shfl_xor(tm, 2));
      tm = fmaxf(tm, __shfl_xor(tm, 4));
      tm = fmaxf(tm, __shfl_xor(tm, 8));
      float mn = fmaxf(m4[i], tm);
      float te = 0.f;
#pragma unroll
      for (int nf = 0; nf < 8; ++nf) te += __expf(sacc[nf][i] * 0.125f - mn);
      te += __shfl_xor(te, 1);
      te += __shfl_xor(te, 2);
      te += __shfl_xor(te, 4);
      te += __shfl_xor(te, 8);
      s4[i] = s4[i] * __expf(m4[i] - mn) + te;
      m4[i] = mn;
    }
  }

  float inv4[4];
#pragma unroll
  for (int i = 0; i < 4; ++i) inv4[i] = 1.f / s4[i];

  f32x4 pacc[4];
#pragma unroll
  for (int nv = 0; nv < 4; ++nv) pacc[nv] = (f32x4){0.f, 0.f, 0.f, 0.f};

  // ---- pass 2: recompute, write scores, accumulate PV ----
  for (int t0 = 0; t0 < 1024; t0 += 128) {
    f32x4 sacc[8];
#pragma unroll
    for (int nf = 0; nf < 8; ++nf) sacc[nf] = (f32x4){0.f, 0.f, 0.f, 0.f};
#pragma unroll
    for (int nf = 0; nf < 8; ++nf) {
      const short* kr = kg + (long)(t0 + nf * 16 + fr) * 1024;
      short8 b0 = *(const short8*)kr;
      short8 b1 = *(const short8*)(kr + 32);
      sacc[nf] = __builtin_amdgcn_mfma_f32_16x16x32_bf16(aq0, b0, sacc[nf], 0, 0, 0);
      sacc[nf] = __builtin_amdgcn_mfma_f32_16x16x32_bf16(aq1, b1, sacc[nf], 0, 0, 0);
    }
#pragma unroll
    for (int nf = 0; nf < 8; ++nf) {
#pragma unroll
      for (int i = 0; i < 4; ++i) {
        float p = __expf(sacc[nf][i] * 0.125f - m4[i]) * inv4[i];
        scores[((long)z << 20) + ((long)(q0 + w * 16 + khi * 4 + i) << 10) + t0 +
               nf * 16 + fr] = p;
        Ps[(w * 16 + khi * 4 + i) * LP + nf * 16 + fr] = f2bf(p);
      }
    }
    // PV: Ps rows wave-private; V fragments straight from L2-resident vt
#pragma unroll
    for (int ks = 0; ks < 128; ks += 32) {
      short8 ap = *(const short8*)&Ps[(w * 16 + fr) * LP + ks + khi * 8];
#pragma unroll
      for (int nv = 0; nv < 4; ++nv) {
        short8 bv = *(const short8*)(vt + bqk +
                                     ((long)((nv * 16 + fr) * 16 + g) << 10) + t0 + ks +
                                     khi * 8);
        pacc[nv] = __builtin_amdgcn_mfma_f32_16x16x32_bf16(ap, bv, pacc[nv], 0, 0, 0);
      }
    }
  }

#pragma unroll
  for (int nv = 0; nv < 4; ++nv)
#pragma unroll
    for (int i = 0; i < 4; ++i)
      at[bqk + ((long)(q0 + w * 16 + khi * 4 + i) << 10) + (nv * 16 + fr) * 16 + g] =
          f2bf(pacc[nv][i]);
}

// one wave per 1024-elem row
__global__ __launch_bounds__(256) void layernorm_rows(const float* __restrict__ X,
                                                      const float* __restrict__ gamma,
                                                      const float* __restrict__ beta,
                                                      float* __restrict__ O) {
  const int row = blockIdx.x * 4 + (threadIdx.x >> 6);
  const int lane = threadIdx.x & 63;
  const float* x = X + (long)row * 1024 + lane * 4;
  f32x4 v[4];
  float s = 0.f, sq = 0.f;
#pragma unroll
  for (int j = 0; j < 4; ++j) {
    v[j] = *(const f32x4*)(x + j * 256);
#pragma unroll
    for (int e = 0; e < 4; ++e) {
      s += v[j][e];
      sq += v[j][e] * v[j][e];
    }
  }
#pragma unroll
  for (int off = 32; off; off >>= 1) {
    s += __shfl_xor(s, off);
    sq += __shfl_xor(sq, off);
  }
  const float mu = s * (1.f / 1024.f);
  const float var = sq * (1.f / 1024.f) - mu * mu;
  const float rstd = rsqrtf(var + 1e-5f);
  float* o = O + (long)row * 1024 + lane * 4;
#pragma unroll
  for (int j = 0; j < 4; ++j) {
    f32x4 g = *(const f32x4*)(gamma + lane * 4 + j * 256);
    f32x4 be = *(const f32x4*)(beta + lane * 4 + j * 256);
    f32x4 r;
#pragma unroll
    for (int e = 0; e < 4; ++e) r[e] = (v[j][e] - mu) * rstd * g[e] + be[e];
    *(f32x4*)(o + j * 256) = r;
  }
}

extern "C" void kernel_launch(void* const* d_in, const int* in_sizes, int n_in,
                              void* d_out, int out_size, void* d_ws, size_t ws_size,
                              hipStream_t stream) {
  const float* Q = (const float*)d_in[0];
  const float* KV = (const float*)d_in[1];
  const float* Wq = (const float*)d_in[2];
  const float* bq = (const float*)d_in[3];
  const float* Wk = (const float*)d_in[4];
  const float* bk = (const float*)d_in[5];
  const float* Wv = (const float*)d_in[6];
  const float* bv = (const float*)d_in[7];
  const float* Wp = (const float*)d_in[8];
  const float* bp = (const float*)d_in[9];
  const float* gamma = (const float*)d_in[10];
  const float* beta = (const float*)d_in[11];

  float* out = (float*)d_out;                       // [4M] f32
  float* scores = out + (long)4 * 1024 * 1024;      // [64M] f32

  char* ws = (char*)d_ws;
  short* Wqb = (short*)(ws);                        // 2MB each
  short* Wkb = (short*)(ws + (2L << 20));
  short* Wvb = (short*)(ws + (4L << 20));
  short* Wpb = (short*)(ws + (6L << 20));
  short* qb = (short*)(ws + (8L << 20));            // 8MB
  short* kb = (short*)(ws + (16L << 20));           // 8MB
  short* vt = (short*)(ws + (24L << 20));           // 8MB
  short* at = (short*)(ws + (32L << 20));           // 8MB
  float* pre = (float*)(ws + (40L << 20));          // 16MB -> peak 56MB
  (void)ws_size; (void)in_sizes; (void)n_in; (void)out_size;

  // 1) weight f32 -> bf16 conversions (Q/KV conversion fused into GEMM staging)
  convert_f32_bf16<<<512, 256, 0, stream>>>(Wq, Wqb, 131072);
  convert_f32_bf16<<<512, 256, 0, stream>>>(Wk, Wkb, 131072);
  convert_f32_bf16<<<512, 256, 0, stream>>>(Wv, Wvb, 131072);
  convert_f32_bf16<<<512, 256, 0, stream>>>(Wp, Wpb, 131072);

  // 2) projections (A read as f32, converted in staging)
  gemm_mfma<0, true, short><<<1024, 256, 0, stream>>>(
      Q, 1024, Wqb, 1024, qb, 1024, bq, nullptr, 0, 1.f, 1024, 16);
  gemm_mfma<0, true, short><<<1024, 256, 0, stream>>>(
      KV, 1024, Wkb, 1024, kb, 1024, bk, nullptr, 0, 1.f, 1024, 16);
  gemm_mfma<1, true, short><<<1024, 256, 0, stream>>>(
      KV, 1024, Wvb, 1024, vt, 1024, bv, nullptr, 0, 1.f, 1024, 16);

  // 3) fused logits+softmax+PV: writes scores (d_out) and at (bf16)
  fused_attn<<<1024, 256, 0, stream>>>(qb, kb, vt, scores, at);

  // 4) pre = at@Wp^T + bp + Q
  gemm_mfma<0, false, float><<<1024, 256, 0, stream>>>(
      at, 1024, Wpb, 1024, pre, 1024, bp, Q, 1024, 1.f, 1024, 16);

  // 5) LayerNorm -> out
  layernorm_rows<<<1024, 256, 0, stream>>>(pre, gamma, beta, out);
}